// Round 1
// baseline (10555.123 us; speedup 1.0000x reference)
//
#include <hip/hip_runtime.h>
#include <cstdint>
#include <cstddef>

// Problem constants
#define BB 32
#define TT 256
#define HID 512
// ws layout (floats)
//  x0     : 8192*350   = 2,867,200
//  xp_fw  : 8192*2048  = 16,777,216
//  xp_bw  : 16,777,216
//  out0   : 8192*1024  = 8,388,608
//  out1   : 8,388,608
//  hT     : 2 dir * 2 buf * 512*32 = 65,536
//  cbuf   : 2 dir * 512*32         = 32,768

// ---------------- embedding + concat ----------------
__global__ __launch_bounds__(256) void embed_kernel(
    const int* __restrict__ ids, const int* __restrict__ msk,
    const float* __restrict__ emb, const float* __restrict__ memb,
    float* __restrict__ x0)
{
  int bt = blockIdx.x;            // 0..8191
  int id = ids[bt];
  int m  = msk[bt];
  const float* er = emb  + (size_t)id * 300;
  const float* mr = memb + (size_t)m * 50;
  for (int d = threadIdx.x; d < 350; d += 256) {
    x0[(size_t)bt * 350 + d] = (d < 300) ? er[d] : mr[d - 300];
  }
}

// ---------------- fp32 GEMM: C(M x 2048) = A(M x K) @ W(K x 2048) + bias ----
__global__ __launch_bounds__(256) void gemm_proj(
    const float* __restrict__ A, const float* __restrict__ W,
    const float* __restrict__ bias, float* __restrict__ C,
    int M, int K)
{
  const int N = 2048;
  __shared__ float As[16][128];
  __shared__ float Bs[16][128];
  int tid = threadIdx.x;
  int m0 = blockIdx.x * 128;
  int n0 = blockIdx.y * 128;
  int ty = tid >> 4, tx = tid & 15;
  float acc[8][8];
#pragma unroll
  for (int i = 0; i < 8; ++i) {
#pragma unroll
    for (int j = 0; j < 8; ++j) acc[i][j] = 0.f;
  }
  for (int k0 = 0; k0 < K; k0 += 16) {
#pragma unroll
    for (int i = 0; i < 8; ++i) {
      int e = tid + i * 256;
      int row = e >> 4, kk = e & 15;
      float v = (k0 + kk < K) ? A[(size_t)(m0 + row) * K + k0 + kk] : 0.f;
      As[kk][row] = v;
    }
#pragma unroll
    for (int i = 0; i < 2; ++i) {
      int e = tid + i * 256;
      int kk = e >> 5, c4 = (e & 31) << 2;
      float4 v = make_float4(0.f, 0.f, 0.f, 0.f);
      if (k0 + kk < K) v = *(const float4*)(W + (size_t)(k0 + kk) * N + n0 + c4);
      *(float4*)&Bs[kk][c4] = v;
    }
    __syncthreads();
#pragma unroll
    for (int kk = 0; kk < 16; ++kk) {
      float a[8], b[8];
      *(float4*)&a[0] = *(const float4*)&As[kk][ty * 8];
      *(float4*)&a[4] = *(const float4*)&As[kk][ty * 8 + 4];
      *(float4*)&b[0] = *(const float4*)&Bs[kk][tx * 8];
      *(float4*)&b[4] = *(const float4*)&Bs[kk][tx * 8 + 4];
#pragma unroll
      for (int i = 0; i < 8; ++i) {
#pragma unroll
        for (int j = 0; j < 8; ++j) acc[i][j] = fmaf(a[i], b[j], acc[i][j]);
      }
    }
    __syncthreads();
  }
#pragma unroll
  for (int i = 0; i < 8; ++i) {
    int row = m0 + ty * 8 + i;
#pragma unroll
    for (int jv = 0; jv < 2; ++jv) {
      int col = n0 + tx * 8 + jv * 4;
      float4 o;
      o.x = acc[i][jv * 4 + 0] + bias[col + 0];
      o.y = acc[i][jv * 4 + 1] + bias[col + 1];
      o.z = acc[i][jv * 4 + 2] + bias[col + 2];
      o.w = acc[i][jv * 4 + 3] + bias[col + 3];
      *(float4*)(C + (size_t)row * N + col) = o;
    }
  }
}

// ---------------- one LSTM timestep, both directions ----------------
// grid 256 WGs: wg<128 -> fw, wg>=128 -> bw. Each WG owns 4 hidden units
// (16 gate columns). LDS: Wl[512][16] (32KB) + hs[512][32] (64KB) + zs[8][512]
// (16KB) = 112KB dynamic.
__global__ __launch_bounds__(256) void lstm_step(
    const float* __restrict__ xp_fw, const float* __restrict__ xp_bw,
    const float* __restrict__ w_fw, const float* __restrict__ w_bw,
    int din,
    const int* __restrict__ length,
    float* __restrict__ out,      // (B,T,1024)
    float* __restrict__ hT,       // [dir][2][512][32]
    float* __restrict__ cbuf,     // [dir][512][32]
    int t)
{
  extern __shared__ float smem[];
  float* Wl = smem;              // [512][16]
  float* hs = smem + 512 * 16;   // [512][32]
  float* zs = hs + 512 * 32;     // [8][512]
  int tid = threadIdx.x;
  int wg = blockIdx.x;
  int dir = wg >> 7;
  int wd = wg & 127;
  int u0 = wd << 2;
  const float* Wm = dir ? w_bw : w_fw;
  const float* xp = dir ? xp_bw : xp_fw;
  const float* hTr = hT + (size_t)dir * 32768 + (size_t)(t & 1) * 16384;
  float* hTw = hT + (size_t)dir * 32768 + (size_t)((t & 1) ^ 1) * 16384;
  float* cb = cbuf + (size_t)dir * 16384;

  // load recurrent-weight slice: Wl[k][c], c = q*4+j  <->  W col q*512+u0+j
  {
    const float* wbase = Wm + (size_t)din * 2048 + u0;
#pragma unroll
    for (int kk = 0; kk < 2; ++kk) {
      int k = tid * 2 + kk;
      const float* wr = wbase + (size_t)k * 2048;
#pragma unroll
      for (int q = 0; q < 4; ++q) {
        *(float4*)&Wl[k * 16 + q * 4] = *(const float4*)(wr + q * 512);
      }
    }
  }
  // stage h (prev step) : linear copy, hT layout already [k][b]
#pragma unroll
  for (int i = 0; i < 16; ++i) {
    int e = (tid + i * 256) * 4;
    *(float4*)&hs[e] = *(const float4*)&hTr[e];
  }
  __syncthreads();

  // partial z: thread = (ks, 4 cols, 4 batches), k-split 8
  int ks = tid >> 5;
  int tile = tid & 31;
  int c0 = (tile & 3) << 2;
  int b0 = (tile >> 2) << 2;
  float acc[4][4];
#pragma unroll
  for (int i = 0; i < 4; ++i) {
#pragma unroll
    for (int j = 0; j < 4; ++j) acc[i][j] = 0.f;
  }
  int kbeg = ks << 6;
  for (int k = kbeg; k < kbeg + 64; ++k) {
    float4 w4 = *(const float4*)&Wl[k * 16 + c0];
    float4 h4 = *(const float4*)&hs[k * 32 + b0];
    acc[0][0] = fmaf(w4.x, h4.x, acc[0][0]);
    acc[0][1] = fmaf(w4.x, h4.y, acc[0][1]);
    acc[0][2] = fmaf(w4.x, h4.z, acc[0][2]);
    acc[0][3] = fmaf(w4.x, h4.w, acc[0][3]);
    acc[1][0] = fmaf(w4.y, h4.x, acc[1][0]);
    acc[1][1] = fmaf(w4.y, h4.y, acc[1][1]);
    acc[1][2] = fmaf(w4.y, h4.z, acc[1][2]);
    acc[1][3] = fmaf(w4.y, h4.w, acc[1][3]);
    acc[2][0] = fmaf(w4.z, h4.x, acc[2][0]);
    acc[2][1] = fmaf(w4.z, h4.y, acc[2][1]);
    acc[2][2] = fmaf(w4.z, h4.z, acc[2][2]);
    acc[2][3] = fmaf(w4.z, h4.w, acc[2][3]);
    acc[3][0] = fmaf(w4.w, h4.x, acc[3][0]);
    acc[3][1] = fmaf(w4.w, h4.y, acc[3][1]);
    acc[3][2] = fmaf(w4.w, h4.z, acc[3][2]);
    acc[3][3] = fmaf(w4.w, h4.w, acc[3][3]);
  }
#pragma unroll
  for (int ci = 0; ci < 4; ++ci) {
    *(float4*)&zs[ks * 512 + (c0 + ci) * 32 + b0] =
        make_float4(acc[ci][0], acc[ci][1], acc[ci][2], acc[ci][3]);
  }
  __syncthreads();

  if (tid < 128) {
    int u = tid >> 5;      // 0..3
    int b = tid & 31;      // batch
    int L = length[b];
    bool active = t < L;
    int ug = u0 + u;
    int pos = dir ? (active ? (L - 1 - t) : t) : t;
    const float* xr = xp + ((size_t)(b * TT + pos)) * 2048 + ug;
    float z[4];
#pragma unroll
    for (int q = 0; q < 4; ++q) {
      float s = xr[(size_t)q * 512];
#pragma unroll
      for (int p = 0; p < 8; ++p) s += zs[p * 512 + (q * 4 + u) * 32 + b];
      z[q] = s;
    }
    float c_old = cb[ug * 32 + b];
    float h_old = hs[ug * 32 + b];
    float si = 1.f / (1.f + expf(-z[0]));
    float sj = tanhf(z[1]);
    float sf = 1.f / (1.f + expf(-(z[2] + 1.f)));
    float so = 1.f / (1.f + expf(-z[3]));
    float cn = sf * c_old + si * sj;
    float hn = so * tanhf(cn);
    if (active) cb[ug * 32 + b] = cn;
    hTw[ug * 32 + b] = active ? hn : h_old;
    out[((size_t)(b * TT + pos)) * 1024 + dir * 512 + ug] = active ? hn : 0.f;
  }
}

// ---------------- CRF + pooling + final softmax ----------------
__global__ __launch_bounds__(256) void crf_final(
    const float* __restrict__ out1,   // (B,T,1024)
    const float* __restrict__ crf_w, const float* __restrict__ crf_b,
    const float* __restrict__ trans,
    const int* __restrict__ length,
    const float* __restrict__ lw, const float* __restrict__ lb,
    float* __restrict__ dout)
{
  __shared__ float e[TT][2];
  __shared__ float pw[TT];
  __shared__ float sv[1024];
  __shared__ float red[256];
  int b = blockIdx.x, tid = threadIdx.x;
  int lane = tid & 63, w = tid >> 6;
  const float* ob = out1 + (size_t)b * TT * 1024;
  // e = out1 @ crf_w + crf_b
  for (int t = w; t < TT; t += 4) {
    float a0 = 0.f, a1 = 0.f;
    for (int i = 0; i < 16; ++i) {
      int d = lane + i * 64;
      float v = ob[(size_t)t * 1024 + d];
      a0 += v * crf_w[d * 2];
      a1 += v * crf_w[d * 2 + 1];
    }
    for (int off = 32; off; off >>= 1) {
      a0 += __shfl_down(a0, off);
      a1 += __shfl_down(a1, off);
    }
    if (lane == 0) { e[t][0] = a0 + crf_b[0]; e[t][1] = a1 + crf_b[1]; }
  }
  __syncthreads();
  if (tid == 0) {
    int L = length[b];
    float t00 = trans[0], t01 = trans[1], t10 = trans[2], t11 = trans[3];
    float a0 = e[0][0], a1 = e[0][1];
    {
      float m = fmaxf(a0, a1);
      float e0 = expf(a0 - m), e1 = expf(a1 - m);
      pw[0] = (L > 0) ? (e1 / (e0 + e1)) : 0.f;
    }
    for (int t = 1; t < TT; ++t) {
      if (t < L) {
        float x0 = a0 + t00, y0 = a1 + t10;
        float m0 = fmaxf(x0, y0);
        float n0 = m0 + logf(expf(x0 - m0) + expf(y0 - m0)) + e[t][0];
        float x1 = a0 + t01, y1 = a1 + t11;
        float m1 = fmaxf(x1, y1);
        float n1 = m1 + logf(expf(x1 - m1) + expf(y1 - m1)) + e[t][1];
        a0 = n0; a1 = n1;
        float m = fmaxf(a0, a1);
        float e0 = expf(a0 - m), e1 = expf(a1 - m);
        pw[t] = e1 / (e0 + e1);
      } else {
        pw[t] = 0.f;
      }
    }
  }
  __syncthreads();
  // sv = sum_t pw[t] * out1[t,:]
  for (int i = 0; i < 4; ++i) {
    int d = tid + i * 256;
    float s = 0.f;
    for (int t = 0; t < TT; ++t) s += pw[t] * ob[(size_t)t * 1024 + d];
    sv[d] = s;
  }
  __syncthreads();
  // logits = softmax(sv @ lw + lb)
  float v[3];
  for (int c = 0; c < 3; ++c) {
    float s = 0.f;
    for (int i = 0; i < 4; ++i) {
      int d = tid + i * 256;
      s += sv[d] * lw[d * 3 + c];
    }
    red[tid] = s;
    __syncthreads();
    for (int off = 128; off; off >>= 1) {
      if (tid < off) red[tid] += red[tid + off];
      __syncthreads();
    }
    if (tid == 0) v[c] = red[0] + lb[c];
    __syncthreads();
  }
  if (tid == 0) {
    float m = fmaxf(v[0], fmaxf(v[1], v[2]));
    float e0 = expf(v[0] - m), e1 = expf(v[1] - m), e2 = expf(v[2] - m);
    float s = e0 + e1 + e2;
    dout[b * 3 + 0] = e0 / s;
    dout[b * 3 + 1] = e1 / s;
    dout[b * 3 + 2] = e2 / s;
  }
}

extern "C" void kernel_launch(void* const* d_in, const int* in_sizes, int n_in,
                              void* d_out, int out_size, void* d_ws, size_t ws_size,
                              hipStream_t stream) {
  (void)in_sizes; (void)n_in; (void)out_size; (void)ws_size;
  const int* ids    = (const int*)d_in[0];
  const int* msk    = (const int*)d_in[1];
  const int* len    = (const int*)d_in[2];
  const float* emb  = (const float*)d_in[3];
  const float* memb = (const float*)d_in[4];
  const float* trans= (const float*)d_in[5];
  const float* w_fw0= (const float*)d_in[6];
  const float* b_fw0= (const float*)d_in[7];
  const float* w_bw0= (const float*)d_in[8];
  const float* b_bw0= (const float*)d_in[9];
  const float* w_fw1= (const float*)d_in[10];
  const float* b_fw1= (const float*)d_in[11];
  const float* w_bw1= (const float*)d_in[12];
  const float* b_bw1= (const float*)d_in[13];
  const float* crf_w= (const float*)d_in[14];
  const float* crf_b= (const float*)d_in[15];
  const float* lw   = (const float*)d_in[16];
  const float* lb   = (const float*)d_in[17];
  float* outp = (float*)d_out;

  float* ws    = (float*)d_ws;
  float* x0    = ws;
  float* xp_fw = x0 + 2867200;
  float* xp_bw = xp_fw + 16777216;
  float* out0  = xp_bw + 16777216;
  float* out1  = out0 + 8388608;
  float* hT    = out1 + 8388608;
  float* cbuf_ = hT + 65536;

  hipFuncSetAttribute(reinterpret_cast<const void*>(lstm_step),
                      hipFuncAttributeMaxDynamicSharedMemorySize, 114688);

  embed_kernel<<<8192, 256, 0, stream>>>(ids, msk, emb, memb, x0);

  dim3 gg(64, 16);
  gemm_proj<<<gg, 256, 0, stream>>>(x0, w_fw0, b_fw0, xp_fw, 8192, 350);
  gemm_proj<<<gg, 256, 0, stream>>>(x0, w_bw0, b_bw0, xp_bw, 8192, 350);

  hipMemsetAsync(hT, 0, (65536 + 32768) * sizeof(float), stream);
  for (int t = 0; t < TT; ++t) {
    lstm_step<<<256, 256, 114688, stream>>>(xp_fw, xp_bw, w_fw0, w_bw0, 350,
                                            len, out0, hT, cbuf_, t);
  }

  gemm_proj<<<gg, 256, 0, stream>>>(out0, w_fw1, b_fw1, xp_fw, 8192, 1024);
  gemm_proj<<<gg, 256, 0, stream>>>(out0, w_bw1, b_bw1, xp_bw, 8192, 1024);

  hipMemsetAsync(hT, 0, (65536 + 32768) * sizeof(float), stream);
  for (int t = 0; t < TT; ++t) {
    lstm_step<<<256, 256, 114688, stream>>>(xp_fw, xp_bw, w_fw1, w_bw1, 1024,
                                            len, out1, hT, cbuf_, t);
  }

  crf_final<<<32, 256, 0, stream>>>(out1, crf_w, crf_b, trans, len, lw, lb, outp);
}